// Round 1
// baseline (1446.255 us; speedup 1.0000x reference)
//
#include <hip/hip_runtime.h>
#include <stdint.h>
#include <math.h>

#define N_NODES 50000
#define N_EDGES 1500000
#define HDIM 128
#define TDIM 100
#define MSG 484   // 3*HDIM + TDIM
#define BM 32
#define PITCH 488 // 484 padded to 16B multiple

__global__ void init_keys_kernel(unsigned long long* __restrict__ keys) {
    int i = blockIdx.x * 256 + threadIdx.x;
    if (i < N_NODES) keys[i] = 0ULL;
}

__global__ void scan_edges_kernel(const int* __restrict__ dst,
                                  const float* __restrict__ edge_ts,
                                  unsigned long long* __restrict__ keys) {
    int e = blockIdx.x * 256 + threadIdx.x;
    if (e < N_EDGES) {
        // edge_ts >= 0 so IEEE bits are order-preserving; +1 so key==0 means "no msg";
        // low word tie-breaks toward max edge index, matching the reference.
        unsigned long long key =
            ((unsigned long long)__float_as_uint(edge_ts[e]) << 32) | (unsigned int)(e + 1);
        atomicMax(&keys[dst[e]], key);
    }
}

__device__ __forceinline__ float sigmoidf_(float x) {
    return 1.0f / (1.0f + __expf(-x));
}

__global__ __launch_bounds__(256, 2)
void gru_kernel(const int* __restrict__ src,
                const float* __restrict__ edge_ts,
                const float* __restrict__ ef,
                const float* __restrict__ mem,
                const float* __restrict__ lut,
                const float* __restrict__ tw,
                const float* __restrict__ tb,
                const float* __restrict__ Wih,
                const float* __restrict__ Whh,
                const float* __restrict__ bih,
                const float* __restrict__ bhh,
                const unsigned long long* __restrict__ keys,
                float* __restrict__ out) {
    __shared__ float A[BM][PITCH];              // m_bar rows: [mem_s[src] | mem_s[n] | ef[w] | tenc]
    __shared__ int sh_src[BM], sh_e[BM], sh_has[BM];
    __shared__ float sh_ts[BM], sh_delta[BM];

    const int tid = threadIdx.x;
    const int base = blockIdx.x * BM;

    // ---- phase 0: per-node winner decode ----
    if (tid < BM) {
        int n = base + tid;
        int has = 0, e = 0, s = 0;
        float tsv = 0.f, delta = 0.f;
        if (n < N_NODES) {
            unsigned long long key = keys[n];
            has = (key != 0ULL);
            e = has ? (int)((unsigned int)key - 1u) : 0;  // safe index 0 when empty (like jnp.clip)
            s = src[e];
            float tv = edge_ts[e];
            delta = tv - lut[s];
            tsv = has ? tv : lut[n];
        }
        sh_src[tid] = s; sh_e[tid] = e; sh_has[tid] = has;
        sh_ts[tid] = tsv; sh_delta[tid] = delta;
    }
    __syncthreads();

    // ---- phase 1: stage m_bar into LDS (8 threads per node) ----
    {
        const int i = tid >> 3, l8 = tid & 7;
        const int n = base + i;
        if (n < N_NODES) {
            const int s = sh_src[i], e = sh_e[i];
            const float4* ms = (const float4*)(mem + (size_t)s * HDIM);
            const float4* mn = (const float4*)(mem + (size_t)n * HDIM);
            const float4* fe = (const float4*)(ef + (size_t)e * HDIM);
            #pragma unroll
            for (int p = 0; p < 4; ++p) {
                int c4 = p * 8 + l8;   // float4 index 0..31
                *(float4*)&A[i][c4 * 4]            = ms[c4];
                *(float4*)&A[i][HDIM + c4 * 4]     = mn[c4];
                *(float4*)&A[i][2 * HDIM + c4 * 4] = fe[c4];
            }
            const float d = sh_delta[i];
            for (int q = l8; q < TDIM; q += 8)
                A[i][3 * HDIM + q] = cosf(fmaf(d, tw[q], tb[q]));
        }
    }
    __syncthreads();

    // ---- phase 2: register-tiled GEMM ----
    // 256 threads = 8 M-groups x 32 N-lanes. Thread: 4 nodes x 12 cols (stride 32).
    const int tm = tid >> 5;   // 0..7
    const int tn = tid & 31;   // 0..31

    float acc[4][12];   // W_ih (+W_hh for r,z gates) accumulation; cols tn+32*j
    float acch[4][4];   // W_hh accumulation for n-gate cols (j=8..11)
    #pragma unroll
    for (int i = 0; i < 4; ++i) {
        #pragma unroll
        for (int j = 0; j < 12; ++j) acc[i][j] = 0.f;
        #pragma unroll
        for (int j = 0; j < 4; ++j) acch[i][j] = 0.f;
    }

    // W_ih: k in [0, 484)
    #pragma unroll 1
    for (int k4 = 0; k4 < MSG / 4; ++k4) {
        const int k = k4 * 4;
        float4 b[12];
        #pragma unroll
        for (int j = 0; j < 12; ++j)
            b[j] = *(const float4*)(Wih + (size_t)(tn + 32 * j) * MSG + k);
        #pragma unroll
        for (int i = 0; i < 4; ++i) {
            const float4 a = *(const float4*)&A[tm * 4 + i][k];
            #pragma unroll
            for (int j = 0; j < 12; ++j) {
                acc[i][j] = fmaf(a.x, b[j].x, acc[i][j]);
                acc[i][j] = fmaf(a.y, b[j].y, acc[i][j]);
                acc[i][j] = fmaf(a.z, b[j].z, acc[i][j]);
                acc[i][j] = fmaf(a.w, b[j].w, acc[i][j]);
            }
        }
    }
    // W_hh: k in [0, 128), A slice [128..256)
    #pragma unroll 1
    for (int k4 = 0; k4 < HDIM / 4; ++k4) {
        const int k = k4 * 4;
        float4 b[12];
        #pragma unroll
        for (int j = 0; j < 12; ++j)
            b[j] = *(const float4*)(Whh + (size_t)(tn + 32 * j) * HDIM + k);
        #pragma unroll
        for (int i = 0; i < 4; ++i) {
            const float4 a = *(const float4*)&A[tm * 4 + i][HDIM + k];
            #pragma unroll
            for (int j = 0; j < 8; ++j) {   // r,z gates: i+h share an accumulator
                acc[i][j] = fmaf(a.x, b[j].x, acc[i][j]);
                acc[i][j] = fmaf(a.y, b[j].y, acc[i][j]);
                acc[i][j] = fmaf(a.z, b[j].z, acc[i][j]);
                acc[i][j] = fmaf(a.w, b[j].w, acc[i][j]);
            }
            #pragma unroll
            for (int j = 8; j < 12; ++j) {  // n-gate: keep h part separate
                acch[i][j - 8] = fmaf(a.x, b[j].x, acch[i][j - 8]);
                acch[i][j - 8] = fmaf(a.y, b[j].y, acch[i][j - 8]);
                acch[i][j - 8] = fmaf(a.z, b[j].z, acch[i][j - 8]);
                acch[i][j - 8] = fmaf(a.w, b[j].w, acch[i][j - 8]);
            }
        }
    }

    // ---- phase 3: GRU epilogue ----
    #pragma unroll
    for (int i = 0; i < 4; ++i) {
        const int m = tm * 4 + i;
        const int n = base + m;
        if (n >= N_NODES) continue;
        const bool has = sh_has[m] != 0;
        #pragma unroll
        for (int j = 0; j < 4; ++j) {
            const int c = tn + 32 * j;
            float r = sigmoidf_(acc[i][j]     + bih[c]            + bhh[c]);
            float z = sigmoidf_(acc[i][j + 4] + bih[HDIM + c]     + bhh[HDIM + c]);
            float ng = tanhf(acc[i][j + 8] + bih[2 * HDIM + c]
                             + r * (acch[i][j] + bhh[2 * HDIM + c]));
            float h = A[m][HDIM + c];
            float o = has ? ((1.f - z) * ng + z * h) : h;
            out[(size_t)n * HDIM + c] = o;
        }
        if (tn == 0) out[(size_t)N_NODES * HDIM + n] = sh_ts[m];
    }
}

extern "C" void kernel_launch(void* const* d_in, const int* in_sizes, int n_in,
                              void* d_out, int out_size, void* d_ws, size_t ws_size,
                              hipStream_t stream) {
    const int* src       = (const int*)d_in[0];
    const int* dst       = (const int*)d_in[1];
    const float* edge_ts = (const float*)d_in[2];
    const float* ef      = (const float*)d_in[3];
    const float* mem     = (const float*)d_in[4];
    const float* lut     = (const float*)d_in[5];
    const float* tw      = (const float*)d_in[6];
    const float* tb      = (const float*)d_in[7];
    const float* Wih     = (const float*)d_in[8];
    const float* Whh     = (const float*)d_in[9];
    const float* bih     = (const float*)d_in[10];
    const float* bhh     = (const float*)d_in[11];
    float* out = (float*)d_out;
    unsigned long long* keys = (unsigned long long*)d_ws;  // N_NODES * 8 bytes

    init_keys_kernel<<<(N_NODES + 255) / 256, 256, 0, stream>>>(keys);
    scan_edges_kernel<<<(N_EDGES + 255) / 256, 256, 0, stream>>>(dst, edge_ts, keys);
    gru_kernel<<<(N_NODES + BM - 1) / BM, 256, 0, stream>>>(
        src, edge_ts, ef, mem, lut, tw, tb, Wih, Whh, bih, bhh, keys, out);
}

// Round 2
// 211.156 us; speedup vs baseline: 6.8492x; 6.8492x over previous
//
#include <hip/hip_runtime.h>
#include <stdint.h>
#include <math.h>

#define N_NODES 50000
#define N_EDGES 1500000
#define HDIM 128
#define TDIM 100
#define KPAD 512         // 484 padded to multiple of 32
#define BM 32            // nodes per block

typedef __attribute__((ext_vector_type(8))) short short8v;
typedef __attribute__((ext_vector_type(4))) float f32x4;

__device__ __forceinline__ unsigned short f2bf(float x) {
    unsigned int u = __float_as_uint(x);
    return (unsigned short)((u + 0x7fffu + ((u >> 16) & 1u)) >> 16);
}
__device__ __forceinline__ float sigmoidf_(float x) {
    return 1.0f / (1.0f + __expf(-x));
}
__device__ __forceinline__ float tanhf_(float x) {
    return 2.0f / (1.0f + __expf(-2.0f * x)) - 1.0f;
}

__global__ void init_keys_kernel(unsigned long long* __restrict__ keys) {
    int i = blockIdx.x * 256 + threadIdx.x;
    if (i < N_NODES) keys[i] = 0ULL;
}

__global__ void scan_edges_kernel(const int* __restrict__ dst,
                                  const float* __restrict__ edge_ts,
                                  unsigned long long* __restrict__ keys) {
    int e = blockIdx.x * 256 + threadIdx.x;
    if (e < N_EDGES) {
        // ts >= 0 so IEEE bits are order-preserving; +1 so key==0 means "no msg";
        // low word tie-breaks toward max edge index (matches reference).
        unsigned long long key =
            ((unsigned long long)__float_as_uint(edge_ts[e]) << 32) | (unsigned int)(e + 1);
        atomicMax(&keys[dst[e]], key);
    }
}

// W_ih [384][484] -> bf16 [384][512] (zero-padded), W_hh [384][128] -> bf16.
__global__ void convert_w_kernel(const float* __restrict__ Wih,
                                 const float* __restrict__ Whh,
                                 unsigned short* __restrict__ wb1,
                                 unsigned short* __restrict__ wb2) {
    int idx = blockIdx.x * 256 + threadIdx.x;
    if (idx < 384 * KPAD) {
        int n = idx >> 9, k = idx & (KPAD - 1);
        wb1[idx] = (k < 484) ? f2bf(Wih[n * 484 + k]) : (unsigned short)0;
    } else {
        int j = idx - 384 * KPAD;
        if (j < 384 * HDIM) wb2[j] = f2bf(Whh[j]);
    }
}

__global__ __launch_bounds__(256)
void gru_mfma_kernel(const int* __restrict__ src,
                     const float* __restrict__ edge_ts,
                     const float* __restrict__ ef,
                     const float* __restrict__ mem,
                     const float* __restrict__ lut,
                     const float* __restrict__ tw,
                     const float* __restrict__ tb,
                     const float* __restrict__ bih,
                     const float* __restrict__ bhh,
                     const unsigned short* __restrict__ wb1,   // [384][512] bf16
                     const unsigned short* __restrict__ wb2,   // [384][128] bf16
                     const unsigned long long* __restrict__ keys,
                     float* __restrict__ out) {
    // A rows: [mem_s[src](128) | mem_s[n](128) | ef[w](128) | tenc(100) | 0-pad(28)]
    // XOR-swizzled: element e of row r lives at (e ^ ((r&7)<<3)) (16B-group granular).
    __shared__ unsigned short Alds[BM * KPAD];   // 32 KB
    __shared__ int sh_src[BM], sh_e[BM], sh_has[BM];
    __shared__ float sh_ts[BM], sh_delta[BM];

    const int tid = threadIdx.x;
    const int base = blockIdx.x * BM;

    // ---- phase 0: winner decode ----
    if (tid < BM) {
        int n = base + tid;
        int has = 0, e = 0, s = 0;
        float tsv = 0.f, delta = 0.f;
        if (n < N_NODES) {
            unsigned long long key = keys[n];
            has = (key != 0ULL);
            e = has ? (int)((unsigned int)key - 1u) : 0;
            s = src[e];
            float tv = edge_ts[e];
            delta = tv - lut[s];
            tsv = has ? tv : lut[n];
        }
        sh_src[tid] = s; sh_e[tid] = e; sh_has[tid] = has;
        sh_ts[tid] = tsv; sh_delta[tid] = delta;
    }
    __syncthreads();

    // ts output (one lane per node)
    if (tid < BM && base + tid < N_NODES)
        out[(size_t)N_NODES * HDIM + base + tid] = sh_ts[tid];

    // ---- phase 1: stage A tile as bf16, swizzled ----
    {
        const int i = tid >> 3, l8 = tid & 7;   // 8 threads per node
        const int n = base + i;
        if (n < N_NODES) {
            const int s = sh_src[i], e = sh_e[i];
            const float d = sh_delta[i];
            const int sw = (i & 7) << 3;
            unsigned short* Arow = &Alds[i * KPAD];
            #pragma unroll
            for (int p = 0; p < 8; ++p) {
                const int gk = p * 8 + l8;     // 16B group index 0..63
                const int k0 = gk * 8;
                float f[8];
                if (k0 < 384) {
                    const float* sp = (k0 < 128) ? mem + (size_t)s * HDIM + k0
                                    : (k0 < 256) ? mem + (size_t)n * HDIM + (k0 - 128)
                                                 : ef + (size_t)e * HDIM + (k0 - 256);
                    float4 v0 = *(const float4*)sp;
                    float4 v1 = *(const float4*)(sp + 4);
                    f[0]=v0.x; f[1]=v0.y; f[2]=v0.z; f[3]=v0.w;
                    f[4]=v1.x; f[5]=v1.y; f[6]=v1.z; f[7]=v1.w;
                } else {
                    #pragma unroll
                    for (int j = 0; j < 8; ++j) {
                        int q = k0 - 384 + j;
                        f[j] = (q < TDIM) ? cosf(fmaf(d, tw[q], tb[q])) : 0.f;
                    }
                }
                uint4 pk;
                pk.x = (unsigned)f2bf(f[0]) | ((unsigned)f2bf(f[1]) << 16);
                pk.y = (unsigned)f2bf(f[2]) | ((unsigned)f2bf(f[3]) << 16);
                pk.z = (unsigned)f2bf(f[4]) | ((unsigned)f2bf(f[5]) << 16);
                pk.w = (unsigned)f2bf(f[6]) | ((unsigned)f2bf(f[7]) << 16);
                *(uint4*)&Arow[(k0) ^ sw ? ((k0) ^ sw) : 0] = pk;  // (k0 ^ sw)
            }
        }
    }
    __syncthreads();

    // ---- phase 2: MFMA GEMMs ----
    // 4 waves; wave w owns cols [32w, 32w+32) of EACH gate.
    const int wid = tid >> 6, l = tid & 63;
    const int lr = l & 15, lh = l >> 4;

    const f32x4 fzero = {0.f, 0.f, 0.f, 0.f};
    // acc[q][nf][mf]: q=0 r(i+h), q=1 z(i+h), q=2 i_n, q=3 h_n
    f32x4 acc[4][2][2];
    #pragma unroll
    for (int q = 0; q < 4; ++q)
        #pragma unroll
        for (int nf = 0; nf < 2; ++nf)
            #pragma unroll
            for (int mf = 0; mf < 2; ++mf) acc[q][nf][mf] = fzero;

    // GEMM1: gi = A(0..512) @ W_ih^T
    #pragma unroll 4
    for (int kt = 0; kt < KPAD / 32; ++kt) {
        const int k0 = kt * 32;
        short8v a[2];
        #pragma unroll
        for (int mf = 0; mf < 2; ++mf) {
            const int row = mf * 16 + lr;
            a[mf] = *(const short8v*)&Alds[row * KPAD + ((k0 + lh * 8) ^ ((row & 7) << 3))];
        }
        #pragma unroll
        for (int g3 = 0; g3 < 3; ++g3)
            #pragma unroll
            for (int nf = 0; nf < 2; ++nf) {
                const int nrow = g3 * 128 + wid * 32 + nf * 16 + lr;
                short8v b = *(const short8v*)&wb1[(size_t)nrow * KPAD + k0 + lh * 8];
                #pragma unroll
                for (int mf = 0; mf < 2; ++mf)
                    acc[g3][nf][mf] = __builtin_amdgcn_mfma_f32_16x16x32_bf16(
                        a[mf], b, acc[g3][nf][mf], 0, 0, 0);
            }
    }
    // GEMM2: gh = mem_s @ W_hh^T  (A slice k=128..256)
    #pragma unroll
    for (int kt = 0; kt < 4; ++kt) {
        const int kA = 128 + kt * 32;
        short8v a[2];
        #pragma unroll
        for (int mf = 0; mf < 2; ++mf) {
            const int row = mf * 16 + lr;
            a[mf] = *(const short8v*)&Alds[row * KPAD + ((kA + lh * 8) ^ ((row & 7) << 3))];
        }
        #pragma unroll
        for (int g3 = 0; g3 < 3; ++g3)
            #pragma unroll
            for (int nf = 0; nf < 2; ++nf) {
                const int nrow = g3 * 128 + wid * 32 + nf * 16 + lr;
                short8v b = *(const short8v*)&wb2[(size_t)nrow * HDIM + kt * 32 + lh * 8];
                const int q = (g3 < 2) ? g3 : 3;
                #pragma unroll
                for (int mf = 0; mf < 2; ++mf)
                    acc[q][nf][mf] = __builtin_amdgcn_mfma_f32_16x16x32_bf16(
                        a[mf], b, acc[q][nf][mf], 0, 0, 0);
            }
    }

    // ---- phase 3: GRU epilogue ----
    #pragma unroll
    for (int mf = 0; mf < 2; ++mf)
        #pragma unroll
        for (int nf = 0; nf < 2; ++nf) {
            const int c = wid * 32 + nf * 16 + lr;
            const float b_r = bih[c] + bhh[c];
            const float b_z = bih[HDIM + c] + bhh[HDIM + c];
            const float bi_n = bih[2 * HDIM + c];
            const float bh_n = bhh[2 * HDIM + c];
            #pragma unroll
            for (int ii = 0; ii < 4; ++ii) {
                const int row = mf * 16 + lh * 4 + ii;
                const int node = base + row;
                if (node >= N_NODES) continue;
                const float r = sigmoidf_(acc[0][nf][mf][ii] + b_r);
                const float z = sigmoidf_(acc[1][nf][mf][ii] + b_z);
                const float ng = tanhf_(acc[2][nf][mf][ii] + bi_n +
                                        r * (acc[3][nf][mf][ii] + bh_n));
                const float h = mem[(size_t)node * HDIM + c];
                out[(size_t)node * HDIM + c] =
                    sh_has[row] ? (1.f - z) * ng + z * h : h;
            }
        }
}

extern "C" void kernel_launch(void* const* d_in, const int* in_sizes, int n_in,
                              void* d_out, int out_size, void* d_ws, size_t ws_size,
                              hipStream_t stream) {
    const int* src       = (const int*)d_in[0];
    const int* dst       = (const int*)d_in[1];
    const float* edge_ts = (const float*)d_in[2];
    const float* ef      = (const float*)d_in[3];
    const float* mem     = (const float*)d_in[4];
    const float* lut     = (const float*)d_in[5];
    const float* tw      = (const float*)d_in[6];
    const float* tb      = (const float*)d_in[7];
    const float* Wih     = (const float*)d_in[8];
    const float* Whh     = (const float*)d_in[9];
    const float* bih     = (const float*)d_in[10];
    const float* bhh     = (const float*)d_in[11];
    float* out = (float*)d_out;

    char* ws = (char*)d_ws;
    unsigned long long* keys = (unsigned long long*)ws;            // 400000 B
    unsigned short* wb1 = (unsigned short*)(ws + 400000);          // 384*512*2 = 393216 B
    unsigned short* wb2 = (unsigned short*)(ws + 400000 + 393216); // 384*128*2 =  98304 B

    init_keys_kernel<<<(N_NODES + 255) / 256, 256, 0, stream>>>(keys);
    scan_edges_kernel<<<(N_EDGES + 255) / 256, 256, 0, stream>>>(dst, edge_ts, keys);
    convert_w_kernel<<<(384 * KPAD + 384 * HDIM + 255) / 256, 256, 0, stream>>>(
        Wih, Whh, wb1, wb2);
    gru_mfma_kernel<<<(N_NODES + BM - 1) / BM, 256, 0, stream>>>(
        src, edge_ts, ef, mem, lut, tw, tb, bih, bhh, wb1, wb2, keys, out);
}